// Round 18
// baseline (484.113 us; speedup 1.0000x reference)
//
#include <hip/hip_runtime.h>
#include <hip/hip_bf16.h>
#include <math.h>

// N=50000 nodes, E=800000 edges, D=128, F_IN=8, C=2
// Output float32: [probs E*2 | bbox_pairs E*8 | bbox_index_pairs E*2]

typedef __attribute__((ext_vector_type(8))) short short8;
typedef __attribute__((ext_vector_type(4))) float f32x4;
typedef __attribute__((ext_vector_type(2))) float fv2;

__device__ inline ushort f2bf(float f) {
    union { __hip_bfloat16 h; ushort u; } cv;
    cv.h = __float2bfloat16(f);
    return cv.u;
}
__device__ inline float bf2f(ushort u) {
    union { float f; uint u; } c;
    c.u = ((uint)u) << 16;
    return c.f;
}
__device__ inline uchar f2fp8(float f) {
    uint p = __builtin_amdgcn_cvt_pk_fp8_f32(f, f, 0u, false);
    return (uchar)(p & 0xffu);
}

// ---------------- CSR build ----------------
__global__ void k_hist(const int* __restrict__ col, int* __restrict__ cnt, int E) {
    int e = blockIdx.x * blockDim.x + threadIdx.x;
    if (e < E) atomicAdd(&cnt[col[e]], 1);
}

__global__ __launch_bounds__(1024) void k_bsum(const int* __restrict__ cnt,
                                               int* __restrict__ bsum, int N) {
    __shared__ int ts[1024];
    const int b = blockIdx.x, t = threadIdx.x;
    const int i0 = b * 2048 + 2 * t;
    int a0 = (i0 < N) ? cnt[i0] : 0;
    int a1 = (i0 + 1 < N) ? cnt[i0 + 1] : 0;
    ts[t] = a0 + a1;
    __syncthreads();
#pragma unroll
    for (int off = 512; off > 0; off >>= 1) {
        if (t < off) ts[t] += ts[t + off];
        __syncthreads();
    }
    if (t == 0) bsum[b] = ts[0];
}

__global__ __launch_bounds__(1024) void k_scanw(const int* __restrict__ cnt,
                                                const int* __restrict__ bsum,
                                                int* __restrict__ ptr, int N, int E) {
    __shared__ int ts[1024];
    const int b = blockIdx.x, t = threadIdx.x;
    int boff = 0;
    for (int i = 0; i < b; ++i) boff += bsum[i];
    const int i0 = b * 2048 + 2 * t;
    const int a0 = (i0 < N) ? cnt[i0] : 0;
    const int a1 = (i0 + 1 < N) ? cnt[i0 + 1] : 0;
    const int s = a0 + a1;
    ts[t] = s;
    __syncthreads();
    for (int off = 1; off < 1024; off <<= 1) {
        int v = (t >= off) ? ts[t - off] : 0;
        __syncthreads();
        ts[t] += v;
        __syncthreads();
    }
    const int excl = boff + ts[t] - s;
    if (i0 < N) ptr[i0] = excl;
    if (i0 + 1 < N) ptr[i0 + 1] = excl + a0;
    if (b == 0 && t == 0) ptr[N] = E;
}

// fill CSR: packed (src, norm-bits) in one 8B store
__global__ void k_fill(const int* __restrict__ row, const int* __restrict__ col,
                       const int* __restrict__ cnt, const int* __restrict__ ptr,
                       int* __restrict__ cursor, int2* __restrict__ eadj, int E) {
    int e = blockIdx.x * blockDim.x + threadIdx.x;
    if (e >= E) return;
    int r = row[e], c = col[e];
    float dr = rsqrtf(1.0f + (float)cnt[r]);
    float dc = rsqrtf(1.0f + (float)cnt[c]);
    int p = ptr[c] + atomicAdd(&cursor[c], 1);
    eadj[p] = make_int2(r, __float_as_int(dr * dc));
}

// ---------------- degree-sorted node permutation (counting sort, 256 bins) ----------------
__global__ void k_dhist(const int* __restrict__ cnt, int* __restrict__ dbin, int N) {
    int n = blockIdx.x * blockDim.x + threadIdx.x;
    if (n < N) atomicAdd(&dbin[min(cnt[n], 255)], 1);
}

__global__ __launch_bounds__(256) void k_dscan(const int* __restrict__ dbin,
                                               int* __restrict__ dptr,
                                               int* __restrict__ dcur) {
    __shared__ int ts[256];
    const int t = threadIdx.x;
    const int v0 = dbin[t];
    ts[t] = v0;
    __syncthreads();
    for (int off = 1; off < 256; off <<= 1) {
        int v = (t >= off) ? ts[t - off] : 0;
        __syncthreads();
        ts[t] += v;
        __syncthreads();
    }
    const int excl = ts[t] - v0;
    dptr[t] = excl;
    dcur[t] = excl;
}

__global__ void k_dfill(const int* __restrict__ cnt, int* __restrict__ dcur,
                        int* __restrict__ perm, int N) {
    int n = blockIdx.x * blockDim.x + threadIdx.x;
    if (n < N) {
        int b = min(cnt[n], 255);
        perm[atomicAdd(&dcur[b], 1)] = n;
    }
}

// ---------------- weight prep (fused) ----------------
__global__ void k_prepW(const float* __restrict__ lin1W, const float* __restrict__ W2,
                        ushort* __restrict__ Wuv, ushort* __restrict__ W2t) {
    int tid = blockIdx.x * blockDim.x + threadIdx.x;
    if (tid < 256 * 128) {
        int c = tid >> 7, k = tid & 127;
        int krow = k + ((c >> 7) << 7);
        Wuv[tid] = f2bf(lin1W[krow * 128 + (c & 127)]);
    } else if (tid < 256 * 128 + 128 * 128) {
        int u = tid - 256 * 128;
        int n = u >> 7, k = u & 127;
        W2t[u] = f2bf(W2[k * 128 + n]);
    }
}

// ---------------- fused layer-1 (degree-sorted order): aggregate + GEMM -> x1 bf16 ----------------
__global__ __launch_bounds__(256) void k_l1(const float* __restrict__ feat,
                                            const int* __restrict__ cnt,
                                            const int* __restrict__ ptr,
                                            const int2* __restrict__ eadj,
                                            const int* __restrict__ perm,
                                            const float* __restrict__ W1,
                                            const float* __restrict__ b1,
                                            ushort* __restrict__ x1, int N) {
    __shared__ float sagg[32][8];
    __shared__ float sW1[8 * 128];
    const int tid = threadIdx.x;
    for (int i = tid; i < 1024; i += 256) sW1[i] = W1[i];

    const int lane8 = tid & 7;
    const int nloc = tid >> 3;
    const int idx = blockIdx.x * 32 + nloc;
    const int node = (idx < N) ? perm[idx] : -1;
    float acc = 0.f;
    if (node >= 0) {
        float dd = 1.0f / (1.0f + (float)cnt[node]);
        acc = feat[(size_t)node * 8 + lane8] * dd;
        int i = ptr[node], end = ptr[node + 1];
        for (; i < end; ++i) {
            const int2 a = eadj[i];
            acc += feat[(size_t)a.x * 8 + lane8] * __int_as_float(a.y);
        }
    }
    sagg[nloc][lane8] = acc;
    __syncthreads();

    if (node >= 0) {
        const int jb = lane8 * 16;
        float av[8];
#pragma unroll
        for (int k = 0; k < 8; ++k) av[k] = sagg[nloc][k];
        short8 r0, r1;
#pragma unroll
        for (int j = 0; j < 16; ++j) {
            float s = b1[jb + j];
#pragma unroll
            for (int k = 0; k < 8; ++k) s = fmaf(av[k], sW1[k * 128 + jb + j], s);
            const ushort bv = f2bf(fmaxf(s, 0.f));
            if (j < 8) r0[j] = (short)bv; else r1[j - 8] = (short)bv;
        }
        *reinterpret_cast<short8*>(&x1[(size_t)node * 128 + jb]) = r0;
        *reinterpret_cast<short8*>(&x1[(size_t)node * 128 + jb + 8]) = r1;
    }
}

// ---------------- layer-2 GEMM via MFMA: h2 = fp8(x1[N,128] @ W2) ----------------
__global__ __launch_bounds__(256) void k_gemm2(const ushort* __restrict__ x1,
                                               const ushort* __restrict__ W2t,
                                               uchar* __restrict__ h2, int N) {
    __shared__ ushort ldsW[128 * 128];   // 32 KB, XOR-swizzled (256B rows)
    const int tid = threadIdx.x;
    const int wave = tid >> 6, lane = tid & 63;
    const int m = lane & 15, kb = lane >> 4;
    const int n0 = blockIdx.x * 64;

    const int node_a = min(n0 + wave * 16 + m, N - 1);
    short8 a[4];
#pragma unroll
    for (int kk = 0; kk < 4; ++kk) {
        a[kk] = *reinterpret_cast<const short8*>(&x1[(size_t)node_a * 128 + kk * 32 + kb * 8]);
    }

    {
        char* lb = reinterpret_cast<char*>(ldsW);
        const short8* wg = reinterpret_cast<const short8*>(W2t);
#pragma unroll
        for (int i = 0; i < 8; ++i) {
            const int g = i * 256 + tid;
            const int bo = g * 16;
            const int swz = bo ^ (((bo >> 8) & 7) << 4);
            *reinterpret_cast<short8*>(lb + swz) = wg[g];
        }
    }
    __syncthreads();

    f32x4 acc[8];
#pragma unroll
    for (int t = 0; t < 8; ++t) acc[t] = (f32x4){0.f, 0.f, 0.f, 0.f};

    const char* lbr = reinterpret_cast<const char*>(ldsW);
    const int mswz = (m & 7) << 4;
#pragma unroll
    for (int kk = 0; kk < 4; ++kk) {
#pragma unroll
        for (int t = 0; t < 8; ++t) {
            const int bo = (t * 16 + m) * 256 + kk * 64 + kb * 16;
            const short8 b = *reinterpret_cast<const short8*>(lbr + (bo ^ mswz));
            acc[t] = __builtin_amdgcn_mfma_f32_16x16x32_bf16(a[kk], b, acc[t], 0, 0, 0);
        }
    }

#pragma unroll
    for (int r = 0; r < 4; ++r) {
        const int node = n0 + wave * 16 + kb * 4 + r;
        if (node < N) {
#pragma unroll
            for (int t = 0; t < 8; ++t) {
                h2[(size_t)node * 128 + t * 16 + m] = f2fp8(acc[t][r]);
            }
        }
    }
}

// ---------------- layer-2 aggregate over fp8 h2 (degree-sorted order) ----------------
__global__ __launch_bounds__(256) void k_gather2(const uchar* __restrict__ h2,
                                                 const int* __restrict__ cnt,
                                                 const int* __restrict__ ptr,
                                                 const int2* __restrict__ eadj,
                                                 const int* __restrict__ perm,
                                                 const float* __restrict__ b2,
                                                 ushort* __restrict__ xbf, int N) {
    const int lane8 = threadIdx.x & 7;
    const int idx = blockIdx.x * 32 + (threadIdx.x >> 3);
    if (idx >= N) return;
    const int node = perm[idx];
    const float dd = 1.0f / (1.0f + (float)cnt[node]);
    float acc[16];
    {
        const uint4 w = *reinterpret_cast<const uint4*>(&h2[(size_t)node * 128 + lane8 * 16]);
        const uint ws[4] = {w.x, w.y, w.z, w.w};
#pragma unroll
        for (int q = 0; q < 4; ++q) {
            const fv2 lo = __builtin_amdgcn_cvt_pk_f32_fp8(ws[q], false);
            const fv2 hi = __builtin_amdgcn_cvt_pk_f32_fp8(ws[q], true);
            acc[4 * q + 0] = lo[0] * dd;
            acc[4 * q + 1] = lo[1] * dd;
            acc[4 * q + 2] = hi[0] * dd;
            acc[4 * q + 3] = hi[1] * dd;
        }
    }
    int i = ptr[node];
    const int end = ptr[node + 1];
    for (; i < end; ++i) {
        const int2 aa = eadj[i];
        const float nm = __int_as_float(aa.y);
        const uint4 w = *reinterpret_cast<const uint4*>(&h2[(size_t)aa.x * 128 + lane8 * 16]);
        const uint ws[4] = {w.x, w.y, w.z, w.w};
#pragma unroll
        for (int q = 0; q < 4; ++q) {
            const fv2 lo = __builtin_amdgcn_cvt_pk_f32_fp8(ws[q], false);
            const fv2 hi = __builtin_amdgcn_cvt_pk_f32_fp8(ws[q], true);
            acc[4 * q + 0] = fmaf(lo[0], nm, acc[4 * q + 0]);
            acc[4 * q + 1] = fmaf(lo[1], nm, acc[4 * q + 1]);
            acc[4 * q + 2] = fmaf(hi[0], nm, acc[4 * q + 2]);
            acc[4 * q + 3] = fmaf(hi[1], nm, acc[4 * q + 3]);
        }
    }
    short8 r0, r1;
#pragma unroll
    for (int q = 0; q < 8; ++q) {
        r0[q] = (short)f2bf(fmaxf(acc[q] + b2[lane8 * 16 + q], 0.f));
        r1[q] = (short)f2bf(fmaxf(acc[8 + q] + b2[lane8 * 16 + 8 + q], 0.f));
    }
    *reinterpret_cast<short8*>(&xbf[(size_t)node * 128 + lane8 * 16]) = r0;
    *reinterpret_cast<short8*>(&xbf[(size_t)node * 128 + lane8 * 16 + 8]) = r1;
}

// ---------------- uv GEMM via MFMA: uv[N,256] = fp8(xbf[N,128] @ Wuv^T); bias folded into u ----------------
// Block: 512 thr = 8 waves, 128 nodes. Wave: 16 nodes, loops both col-halves (A-frags reused).
__global__ __launch_bounds__(512) void k_gemm_uv(const ushort* __restrict__ xbf,
                                                 const ushort* __restrict__ Wuv,
                                                 const float* __restrict__ lin1b,
                                                 uchar* __restrict__ uv, int N) {
    __shared__ ushort ldsW[256 * 128];   // 64 KB, XOR-swizzled (256B rows)
    const int tid = threadIdx.x;
    const int wave = tid >> 6, lane = tid & 63;
    const int m = lane & 15, kb = lane >> 4;
    const int n0 = blockIdx.x * 128 + wave * 16;

    const int node_a = min(n0 + m, N - 1);
    short8 a[4];
#pragma unroll
    for (int kk = 0; kk < 4; ++kk) {
        a[kk] = *reinterpret_cast<const short8*>(&xbf[(size_t)node_a * 128 + kk * 32 + kb * 8]);
    }

    {
        char* lb = reinterpret_cast<char*>(ldsW);
        const short8* wg = reinterpret_cast<const short8*>(Wuv);
#pragma unroll
        for (int i = 0; i < 8; ++i) {
            const int g = i * 512 + tid;
            const int bo = g * 16;
            const int swz = bo ^ (((bo >> 8) & 7) << 4);
            *reinterpret_cast<short8*>(lb + swz) = wg[g];
        }
    }
    __syncthreads();

    const char* lbr = reinterpret_cast<const char*>(ldsW);
    const int mswz = (m & 7) << 4;

#pragma unroll
    for (int ch = 0; ch < 2; ++ch) {
        f32x4 acc[8];
#pragma unroll
        for (int t = 0; t < 8; ++t) acc[t] = (f32x4){0.f, 0.f, 0.f, 0.f};
#pragma unroll
        for (int kk = 0; kk < 4; ++kk) {
#pragma unroll
            for (int t = 0; t < 8; ++t) {
                const int bo = (ch * 128 + t * 16 + m) * 256 + kk * 64 + kb * 16;
                const short8 b = *reinterpret_cast<const short8*>(lbr + (bo ^ mswz));
                acc[t] = __builtin_amdgcn_mfma_f32_16x16x32_bf16(a[kk], b, acc[t], 0, 0, 0);
            }
        }
#pragma unroll
        for (int r = 0; r < 4; ++r) {
            const int node = n0 + kb * 4 + r;
            if (node < N) {
#pragma unroll
                for (int t = 0; t < 8; ++t) {
                    const int c = t * 16 + m;
                    float av = acc[t][r];
                    if (ch == 0) av += lin1b[c];
                    uv[(size_t)node * 256 + ch * 128 + c] = f2fp8(av);
                }
            }
        }
    }
}

// ---------------- edge kernel: 8 lanes/edge, uint4 gathers, 2-deep pipeline (proven) ----------------
__global__ __launch_bounds__(256) void k_edge_lite(const uchar* __restrict__ uv,
                                                   const float* __restrict__ linfW,
                                                   const float* __restrict__ linfb,
                                                   const float* __restrict__ bboxes,
                                                   const int* __restrict__ bidx,
                                                   const int* __restrict__ row,
                                                   const int* __restrict__ col,
                                                   float* __restrict__ out_probs,
                                                   float* __restrict__ out_bbox,
                                                   float* __restrict__ out_bidx,
                                                   int E) {
    const int lane8 = threadIdx.x & 7;
    const int slot = threadIdx.x >> 3;       // 32 edges per 256-thr block iteration
    int e = blockIdx.x * 32 + slot;
    if (e >= E) return;

    float wd[16];
#pragma unroll
    for (int j = 0; j < 16; ++j) {
        const int c = lane8 * 16 + j;
        wd[j] = linfW[c * 2] - linfW[c * 2 + 1];
    }
    const float bias_d = linfb[0] - linfb[1];
    const int step = gridDim.x * 32;

    int s = row[e], d = col[e];
    uint4 ua = *reinterpret_cast<const uint4*>(&uv[(size_t)s * 256 + lane8 * 16]);
    uint4 va = *reinterpret_cast<const uint4*>(&uv[(size_t)d * 256 + 128 + lane8 * 16]);

    while (true) {
        const int e2 = e + step;
        const bool more = (e2 < E);
        int s2 = 0, d2 = 0;
        uint4 ua2 = ua, va2 = va;
        if (more) {
            s2 = row[e2];
            d2 = col[e2];
            ua2 = *reinterpret_cast<const uint4*>(&uv[(size_t)s2 * 256 + lane8 * 16]);
            va2 = *reinterpret_cast<const uint4*>(&uv[(size_t)d2 * 256 + 128 + lane8 * 16]);
        }

        float p = 0.f;
        {
            const uint uw[4] = {ua.x, ua.y, ua.z, ua.w};
            const uint vw[4] = {va.x, va.y, va.z, va.w};
#pragma unroll
            for (int w = 0; w < 4; ++w) {
                const fv2 ul = __builtin_amdgcn_cvt_pk_f32_fp8(uw[w], false);
                const fv2 uh = __builtin_amdgcn_cvt_pk_f32_fp8(uw[w], true);
                const fv2 vl = __builtin_amdgcn_cvt_pk_f32_fp8(vw[w], false);
                const fv2 vh = __builtin_amdgcn_cvt_pk_f32_fp8(vw[w], true);
                p = fmaf(fmaxf(ul[0] + vl[0], 0.f), wd[4 * w + 0], p);
                p = fmaf(fmaxf(ul[1] + vl[1], 0.f), wd[4 * w + 1], p);
                p = fmaf(fmaxf(uh[0] + vh[0], 0.f), wd[4 * w + 2], p);
                p = fmaf(fmaxf(uh[1] + vh[1], 0.f), wd[4 * w + 3], p);
            }
        }
        p += __shfl_xor(p, 1);
        p += __shfl_xor(p, 2);
        p += __shfl_xor(p, 4);

        out_bbox[(size_t)e * 8 + lane8] = bboxes[(size_t)((lane8 < 4) ? s : d) * 4 + (lane8 & 3)];
        if (lane8 == 0) {
            *reinterpret_cast<float2*>(&out_bidx[(size_t)e * 2]) =
                make_float2((float)bidx[s], (float)bidx[d]);
        } else if (lane8 == 1) {
            const float dd = p + bias_d;                 // z0 - z1
            const float ad = fabsf(dd);
            const float t = -log1pf(expf(-ad));
            const float2 pr = (dd >= 0.f) ? make_float2(t, t - ad) : make_float2(t - ad, t);
            *reinterpret_cast<float2*>(&out_probs[(size_t)e * 2]) = pr;
        }

        if (!more) break;
        e = e2; s = s2; d = d2; ua = ua2; va = va2;
    }
}

extern "C" void kernel_launch(void* const* d_in, const int* in_sizes, int n_in,
                              void* d_out, int out_size, void* d_ws, size_t ws_size,
                              hipStream_t stream) {
    const float* feat   = (const float*)d_in[0];
    const float* bboxes = (const float*)d_in[1];
    const int*   bidx   = (const int*)d_in[2];
    const int*   eidx   = (const int*)d_in[3];
    const float* W1     = (const float*)d_in[4];
    const float* b1     = (const float*)d_in[5];
    const float* W2     = (const float*)d_in[6];
    const float* b2     = (const float*)d_in[7];
    const float* lin1W  = (const float*)d_in[8];
    const float* lin1b  = (const float*)d_in[9];
    const float* linfW  = (const float*)d_in[10];
    const float* linfb  = (const float*)d_in[11];

    const int N = in_sizes[0] / 8;
    const int E = in_sizes[3] / 2;
    const int* row = eidx;        // sources
    const int* col = eidx + E;    // targets

    size_t Np = ((size_t)N + 255) & ~255ull;
    size_t Ep = ((size_t)E + 255) & ~255ull;
    int*    cnt    = (int*)d_ws;                 // Np
    int*    cursor = cnt + Np;                   // Np   (zeroed with cnt)
    int*    dbin   = cursor + Np;                // 256  (zeroed with cnt)
    int*    ptr    = dbin + 256;                 // Np+256
    int*    bsum   = ptr + Np + 256;             // 256
    int*    dptr   = bsum + 256;                 // 256
    int*    dcur   = dptr + 256;                 // 256
    int*    perm   = dcur + 256;                 // Np
    int2*   eadj   = (int2*)(perm + Np);         // Ep int2 (src, norm-bits)
    ushort* x1     = (ushort*)(eadj + Ep);       // N*128 bf16 (re-used as xbf)
    uchar*  h2     = (uchar*)(x1 + (size_t)N * 128);   // N*128 fp8
    uchar*  uvbuf  = h2 + (size_t)N * 128;       // N*256 fp8
    ushort* Wuv    = (ushort*)(uvbuf + (size_t)N * 256); // 256*128 bf16
    ushort* W2t    = Wuv + 256 * 128;            // 128*128 bf16
    ushort* xbf    = x1;                         // alias: x1 dead after k_gemm2

    float* out       = (float*)d_out;
    float* out_probs = out;                   // E*2
    float* out_bbox  = out + (size_t)E * 2;   // E*8
    float* out_bidx  = out + (size_t)E * 10;  // E*2

    const int B = 256;
    const int nchunk = (N + 2047) / 2048;

    // CSR build + degree-sort + weight prep
    hipMemsetAsync(cnt, 0, (2 * Np + 256) * sizeof(int), stream);  // cnt + cursor + dbin
    k_hist<<<(E + B - 1) / B, B, 0, stream>>>(col, cnt, E);
    k_dhist<<<(N + B - 1) / B, B, 0, stream>>>(cnt, dbin, N);
    k_bsum<<<nchunk, 1024, 0, stream>>>(cnt, bsum, N);
    k_scanw<<<nchunk, 1024, 0, stream>>>(cnt, bsum, ptr, N, E);
    k_dscan<<<1, 256, 0, stream>>>(dbin, dptr, dcur);
    k_dfill<<<(N + B - 1) / B, B, 0, stream>>>(cnt, dcur, perm, N);
    k_fill<<<(E + B - 1) / B, B, 0, stream>>>(row, col, cnt, ptr, cursor, eadj, E);
    k_prepW<<<(256 * 128 + 128 * 128 + B - 1) / B, B, 0, stream>>>(lin1W, W2, Wuv, W2t);

    // layer 1 fused (aggregate + GEMM), degree-sorted node order
    k_l1<<<(N + 31) / 32, B, 0, stream>>>(feat, cnt, ptr, eadj, perm, W1, b1, x1, N);

    // layer 2 (MFMA GEMM -> fp8 h2, then degree-sorted fp8 gather; xbf aliases x1)
    k_gemm2<<<(N + 63) / 64, B, 0, stream>>>(x1, W2t, h2, N);
    k_gather2<<<(N + 31) / 32, B, 0, stream>>>(h2, cnt, ptr, eadj, perm, b2, xbf, N);

    // per-node edge-MLP projections: uv = fp8(xbf @ [W_top|W_bot]), bias folded into u
    k_gemm_uv<<<(N + 127) / 128, 512, 0, stream>>>(xbf, Wuv, lin1b, uvbuf, N);

    // per-edge epilogue + outputs (8 lanes/edge, pipelined, flat order = coalesced writes)
    k_edge_lite<<<2048, B, 0, stream>>>(uvbuf, linfW, linfb,
                                        bboxes, bidx, row, col,
                                        out_probs, out_bbox, out_bidx, E);
}

// Round 19
// 211.488 us; speedup vs baseline: 2.2891x; 2.2891x over previous
//
#include <hip/hip_runtime.h>
#include <hip/hip_bf16.h>
#include <math.h>

// N=50000 nodes, E=800000 edges, D=128, F_IN=8, C=2
// Output float32: [probs E*2 | bbox_pairs E*8 | bbox_index_pairs E*2]

typedef __attribute__((ext_vector_type(8))) short short8;
typedef __attribute__((ext_vector_type(4))) float f32x4;
typedef __attribute__((ext_vector_type(2))) float fv2;

__device__ inline ushort f2bf(float f) {
    union { __hip_bfloat16 h; ushort u; } cv;
    cv.h = __float2bfloat16(f);
    return cv.u;
}
__device__ inline float bf2f(ushort u) {
    union { float f; uint u; } c;
    c.u = ((uint)u) << 16;
    return c.f;
}
__device__ inline uchar f2fp8(float f) {
    uint p = __builtin_amdgcn_cvt_pk_fp8_f32(f, f, 0u, false);
    return (uchar)(p & 0xffu);
}

// ---------------- CSR build ----------------
__global__ void k_hist(const int* __restrict__ col, int* __restrict__ cnt, int E) {
    int e = blockIdx.x * blockDim.x + threadIdx.x;
    if (e < E) atomicAdd(&cnt[col[e]], 1);
}

__global__ __launch_bounds__(1024) void k_bsum(const int* __restrict__ cnt,
                                               int* __restrict__ bsum, int N) {
    __shared__ int ts[1024];
    const int b = blockIdx.x, t = threadIdx.x;
    const int i0 = b * 2048 + 2 * t;
    int a0 = (i0 < N) ? cnt[i0] : 0;
    int a1 = (i0 + 1 < N) ? cnt[i0 + 1] : 0;
    ts[t] = a0 + a1;
    __syncthreads();
#pragma unroll
    for (int off = 512; off > 0; off >>= 1) {
        if (t < off) ts[t] += ts[t + off];
        __syncthreads();
    }
    if (t == 0) bsum[b] = ts[0];
}

__global__ __launch_bounds__(1024) void k_scanw(const int* __restrict__ cnt,
                                                const int* __restrict__ bsum,
                                                int* __restrict__ ptr, int N, int E) {
    __shared__ int ts[1024];
    const int b = blockIdx.x, t = threadIdx.x;
    int boff = 0;
    for (int i = 0; i < b; ++i) boff += bsum[i];
    const int i0 = b * 2048 + 2 * t;
    const int a0 = (i0 < N) ? cnt[i0] : 0;
    const int a1 = (i0 + 1 < N) ? cnt[i0 + 1] : 0;
    const int s = a0 + a1;
    ts[t] = s;
    __syncthreads();
    for (int off = 1; off < 1024; off <<= 1) {
        int v = (t >= off) ? ts[t - off] : 0;
        __syncthreads();
        ts[t] += v;
        __syncthreads();
    }
    const int excl = boff + ts[t] - s;
    if (i0 < N) ptr[i0] = excl;
    if (i0 + 1 < N) ptr[i0 + 1] = excl + a0;
    if (b == 0 && t == 0) ptr[N] = E;
}

// fill CSR: packed (src, norm-bits) in one 8B store
__global__ void k_fill(const int* __restrict__ row, const int* __restrict__ col,
                       const int* __restrict__ cnt, const int* __restrict__ ptr,
                       int* __restrict__ cursor, int2* __restrict__ eadj, int E) {
    int e = blockIdx.x * blockDim.x + threadIdx.x;
    if (e >= E) return;
    int r = row[e], c = col[e];
    float dr = rsqrtf(1.0f + (float)cnt[r]);
    float dc = rsqrtf(1.0f + (float)cnt[c]);
    int p = ptr[c] + atomicAdd(&cursor[c], 1);
    eadj[p] = make_int2(r, __float_as_int(dr * dc));
}

// ---------------- weight prep (fused) ----------------
__global__ void k_prepW(const float* __restrict__ lin1W, const float* __restrict__ W2,
                        ushort* __restrict__ Wuv, ushort* __restrict__ W2t) {
    int tid = blockIdx.x * blockDim.x + threadIdx.x;
    if (tid < 256 * 128) {
        int c = tid >> 7, k = tid & 127;
        int krow = k + ((c >> 7) << 7);
        Wuv[tid] = f2bf(lin1W[krow * 128 + (c & 127)]);
    } else if (tid < 256 * 128 + 128 * 128) {
        int u = tid - 256 * 128;
        int n = u >> 7, k = u & 127;
        W2t[u] = f2bf(W2[k * 128 + n]);
    }
}

// ---------------- fused layer-1: aggregate [N,8] in LDS + GEMM -> x1 bf16 ----------------
__global__ __launch_bounds__(256) void k_l1(const float* __restrict__ feat,
                                            const int* __restrict__ cnt,
                                            const int* __restrict__ ptr,
                                            const int2* __restrict__ eadj,
                                            const float* __restrict__ W1,
                                            const float* __restrict__ b1,
                                            ushort* __restrict__ x1, int N) {
    __shared__ float sagg[32][8];
    __shared__ float sW1[8 * 128];
    const int tid = threadIdx.x;
    for (int i = tid; i < 1024; i += 256) sW1[i] = W1[i];

    const int lane8 = tid & 7;
    const int nloc = tid >> 3;
    const int node = blockIdx.x * 32 + nloc;
    float acc = 0.f;
    if (node < N) {
        float dd = 1.0f / (1.0f + (float)cnt[node]);
        acc = feat[(size_t)node * 8 + lane8] * dd;
        int i = ptr[node], end = ptr[node + 1];
        for (; i < end; ++i) {
            const int2 a = eadj[i];
            acc += feat[(size_t)a.x * 8 + lane8] * __int_as_float(a.y);
        }
    }
    sagg[nloc][lane8] = acc;
    __syncthreads();

    if (node < N) {
        const int jb = lane8 * 16;
        float av[8];
#pragma unroll
        for (int k = 0; k < 8; ++k) av[k] = sagg[nloc][k];
        short8 r0, r1;
#pragma unroll
        for (int j = 0; j < 16; ++j) {
            float s = b1[jb + j];
#pragma unroll
            for (int k = 0; k < 8; ++k) s = fmaf(av[k], sW1[k * 128 + jb + j], s);
            const ushort bv = f2bf(fmaxf(s, 0.f));
            if (j < 8) r0[j] = (short)bv; else r1[j - 8] = (short)bv;
        }
        *reinterpret_cast<short8*>(&x1[(size_t)node * 128 + jb]) = r0;
        *reinterpret_cast<short8*>(&x1[(size_t)node * 128 + jb + 8]) = r1;
    }
}

// ---------------- layer-2 GEMM via MFMA: h2 = fp8(x1[N,128] @ W2) ----------------
__global__ __launch_bounds__(256) void k_gemm2(const ushort* __restrict__ x1,
                                               const ushort* __restrict__ W2t,
                                               uchar* __restrict__ h2, int N) {
    __shared__ ushort ldsW[128 * 128];   // 32 KB, XOR-swizzled (256B rows)
    const int tid = threadIdx.x;
    const int wave = tid >> 6, lane = tid & 63;
    const int m = lane & 15, kb = lane >> 4;
    const int n0 = blockIdx.x * 64;

    const int node_a = min(n0 + wave * 16 + m, N - 1);
    short8 a[4];
#pragma unroll
    for (int kk = 0; kk < 4; ++kk) {
        a[kk] = *reinterpret_cast<const short8*>(&x1[(size_t)node_a * 128 + kk * 32 + kb * 8]);
    }

    {
        char* lb = reinterpret_cast<char*>(ldsW);
        const short8* wg = reinterpret_cast<const short8*>(W2t);
#pragma unroll
        for (int i = 0; i < 8; ++i) {
            const int g = i * 256 + tid;
            const int bo = g * 16;
            const int swz = bo ^ (((bo >> 8) & 7) << 4);
            *reinterpret_cast<short8*>(lb + swz) = wg[g];
        }
    }
    __syncthreads();

    f32x4 acc[8];
#pragma unroll
    for (int t = 0; t < 8; ++t) acc[t] = (f32x4){0.f, 0.f, 0.f, 0.f};

    const char* lbr = reinterpret_cast<const char*>(ldsW);
    const int mswz = (m & 7) << 4;
#pragma unroll
    for (int kk = 0; kk < 4; ++kk) {
#pragma unroll
        for (int t = 0; t < 8; ++t) {
            const int bo = (t * 16 + m) * 256 + kk * 64 + kb * 16;
            const short8 b = *reinterpret_cast<const short8*>(lbr + (bo ^ mswz));
            acc[t] = __builtin_amdgcn_mfma_f32_16x16x32_bf16(a[kk], b, acc[t], 0, 0, 0);
        }
    }

#pragma unroll
    for (int r = 0; r < 4; ++r) {
        const int node = n0 + wave * 16 + kb * 4 + r;
        if (node < N) {
#pragma unroll
            for (int t = 0; t < 8; ++t) {
                h2[(size_t)node * 128 + t * 16 + m] = f2fp8(acc[t][r]);
            }
        }
    }
}

// ---------------- layer-2 aggregate over fp8 h2: 8 lanes/node, uint4 rows ----------------
__global__ __launch_bounds__(256) void k_gather2(const uchar* __restrict__ h2,
                                                 const int* __restrict__ cnt,
                                                 const int* __restrict__ ptr,
                                                 const int2* __restrict__ eadj,
                                                 const float* __restrict__ b2,
                                                 ushort* __restrict__ xbf, int N) {
    const int lane8 = threadIdx.x & 7;
    const int node = blockIdx.x * 32 + (threadIdx.x >> 3);
    if (node >= N) return;
    const float dd = 1.0f / (1.0f + (float)cnt[node]);
    float acc[16];
    {
        const uint4 w = *reinterpret_cast<const uint4*>(&h2[(size_t)node * 128 + lane8 * 16]);
        const uint ws[4] = {w.x, w.y, w.z, w.w};
#pragma unroll
        for (int q = 0; q < 4; ++q) {
            const fv2 lo = __builtin_amdgcn_cvt_pk_f32_fp8(ws[q], false);
            const fv2 hi = __builtin_amdgcn_cvt_pk_f32_fp8(ws[q], true);
            acc[4 * q + 0] = lo[0] * dd;
            acc[4 * q + 1] = lo[1] * dd;
            acc[4 * q + 2] = hi[0] * dd;
            acc[4 * q + 3] = hi[1] * dd;
        }
    }
    int i = ptr[node];
    const int end = ptr[node + 1];
    for (; i < end; ++i) {
        const int2 aa = eadj[i];
        const float nm = __int_as_float(aa.y);
        const uint4 w = *reinterpret_cast<const uint4*>(&h2[(size_t)aa.x * 128 + lane8 * 16]);
        const uint ws[4] = {w.x, w.y, w.z, w.w};
#pragma unroll
        for (int q = 0; q < 4; ++q) {
            const fv2 lo = __builtin_amdgcn_cvt_pk_f32_fp8(ws[q], false);
            const fv2 hi = __builtin_amdgcn_cvt_pk_f32_fp8(ws[q], true);
            acc[4 * q + 0] = fmaf(lo[0], nm, acc[4 * q + 0]);
            acc[4 * q + 1] = fmaf(lo[1], nm, acc[4 * q + 1]);
            acc[4 * q + 2] = fmaf(hi[0], nm, acc[4 * q + 2]);
            acc[4 * q + 3] = fmaf(hi[1], nm, acc[4 * q + 3]);
        }
    }
    short8 r0, r1;
#pragma unroll
    for (int q = 0; q < 8; ++q) {
        r0[q] = (short)f2bf(fmaxf(acc[q] + b2[lane8 * 16 + q], 0.f));
        r1[q] = (short)f2bf(fmaxf(acc[8 + q] + b2[lane8 * 16 + 8 + q], 0.f));
    }
    *reinterpret_cast<short8*>(&xbf[(size_t)node * 128 + lane8 * 16]) = r0;
    *reinterpret_cast<short8*>(&xbf[(size_t)node * 128 + lane8 * 16 + 8]) = r1;
}

// ---------------- uv GEMM via MFMA: uv[N,256] = fp8(xbf[N,128] @ Wuv^T); bias folded into u ----------------
// Block: 512 thr = 8 waves, 128 nodes. Wave: 16 nodes, loops both col-halves (A-frags reused).
__global__ __launch_bounds__(512) void k_gemm_uv(const ushort* __restrict__ xbf,
                                                 const ushort* __restrict__ Wuv,
                                                 const float* __restrict__ lin1b,
                                                 uchar* __restrict__ uv, int N) {
    __shared__ ushort ldsW[256 * 128];   // 64 KB, XOR-swizzled (256B rows)
    const int tid = threadIdx.x;
    const int wave = tid >> 6, lane = tid & 63;
    const int m = lane & 15, kb = lane >> 4;
    const int n0 = blockIdx.x * 128 + wave * 16;

    const int node_a = min(n0 + m, N - 1);
    short8 a[4];
#pragma unroll
    for (int kk = 0; kk < 4; ++kk) {
        a[kk] = *reinterpret_cast<const short8*>(&xbf[(size_t)node_a * 128 + kk * 32 + kb * 8]);
    }

    {
        char* lb = reinterpret_cast<char*>(ldsW);
        const short8* wg = reinterpret_cast<const short8*>(Wuv);
#pragma unroll
        for (int i = 0; i < 8; ++i) {
            const int g = i * 512 + tid;
            const int bo = g * 16;
            const int swz = bo ^ (((bo >> 8) & 7) << 4);
            *reinterpret_cast<short8*>(lb + swz) = wg[g];
        }
    }
    __syncthreads();

    const char* lbr = reinterpret_cast<const char*>(ldsW);
    const int mswz = (m & 7) << 4;

#pragma unroll
    for (int ch = 0; ch < 2; ++ch) {
        f32x4 acc[8];
#pragma unroll
        for (int t = 0; t < 8; ++t) acc[t] = (f32x4){0.f, 0.f, 0.f, 0.f};
#pragma unroll
        for (int kk = 0; kk < 4; ++kk) {
#pragma unroll
            for (int t = 0; t < 8; ++t) {
                const int bo = (ch * 128 + t * 16 + m) * 256 + kk * 64 + kb * 16;
                const short8 b = *reinterpret_cast<const short8*>(lbr + (bo ^ mswz));
                acc[t] = __builtin_amdgcn_mfma_f32_16x16x32_bf16(a[kk], b, acc[t], 0, 0, 0);
            }
        }
#pragma unroll
        for (int r = 0; r < 4; ++r) {
            const int node = n0 + kb * 4 + r;
            if (node < N) {
#pragma unroll
                for (int t = 0; t < 8; ++t) {
                    const int c = t * 16 + m;
                    float av = acc[t][r];
                    if (ch == 0) av += lin1b[c];
                    uv[(size_t)node * 256 + ch * 128 + c] = f2fp8(av);
                }
            }
        }
    }
}

// ---------------- edge kernel: 8 lanes/edge, uint4 gathers, 2-deep pipeline (proven) ----------------
__global__ __launch_bounds__(256) void k_edge_lite(const uchar* __restrict__ uv,
                                                   const float* __restrict__ linfW,
                                                   const float* __restrict__ linfb,
                                                   const float* __restrict__ bboxes,
                                                   const int* __restrict__ bidx,
                                                   const int* __restrict__ row,
                                                   const int* __restrict__ col,
                                                   float* __restrict__ out_probs,
                                                   float* __restrict__ out_bbox,
                                                   float* __restrict__ out_bidx,
                                                   int E) {
    const int lane8 = threadIdx.x & 7;
    const int slot = threadIdx.x >> 3;       // 32 edges per 256-thr block iteration
    int e = blockIdx.x * 32 + slot;
    if (e >= E) return;

    float wd[16];
#pragma unroll
    for (int j = 0; j < 16; ++j) {
        const int c = lane8 * 16 + j;
        wd[j] = linfW[c * 2] - linfW[c * 2 + 1];
    }
    const float bias_d = linfb[0] - linfb[1];
    const int step = gridDim.x * 32;

    int s = row[e], d = col[e];
    uint4 ua = *reinterpret_cast<const uint4*>(&uv[(size_t)s * 256 + lane8 * 16]);
    uint4 va = *reinterpret_cast<const uint4*>(&uv[(size_t)d * 256 + 128 + lane8 * 16]);

    while (true) {
        const int e2 = e + step;
        const bool more = (e2 < E);
        int s2 = 0, d2 = 0;
        uint4 ua2 = ua, va2 = va;
        if (more) {
            s2 = row[e2];
            d2 = col[e2];
            ua2 = *reinterpret_cast<const uint4*>(&uv[(size_t)s2 * 256 + lane8 * 16]);
            va2 = *reinterpret_cast<const uint4*>(&uv[(size_t)d2 * 256 + 128 + lane8 * 16]);
        }

        float p = 0.f;
        {
            const uint uw[4] = {ua.x, ua.y, ua.z, ua.w};
            const uint vw[4] = {va.x, va.y, va.z, va.w};
#pragma unroll
            for (int w = 0; w < 4; ++w) {
                const fv2 ul = __builtin_amdgcn_cvt_pk_f32_fp8(uw[w], false);
                const fv2 uh = __builtin_amdgcn_cvt_pk_f32_fp8(uw[w], true);
                const fv2 vl = __builtin_amdgcn_cvt_pk_f32_fp8(vw[w], false);
                const fv2 vh = __builtin_amdgcn_cvt_pk_f32_fp8(vw[w], true);
                p = fmaf(fmaxf(ul[0] + vl[0], 0.f), wd[4 * w + 0], p);
                p = fmaf(fmaxf(ul[1] + vl[1], 0.f), wd[4 * w + 1], p);
                p = fmaf(fmaxf(uh[0] + vh[0], 0.f), wd[4 * w + 2], p);
                p = fmaf(fmaxf(uh[1] + vh[1], 0.f), wd[4 * w + 3], p);
            }
        }
        p += __shfl_xor(p, 1);
        p += __shfl_xor(p, 2);
        p += __shfl_xor(p, 4);

        out_bbox[(size_t)e * 8 + lane8] = bboxes[(size_t)((lane8 < 4) ? s : d) * 4 + (lane8 & 3)];
        if (lane8 == 0) {
            *reinterpret_cast<float2*>(&out_bidx[(size_t)e * 2]) =
                make_float2((float)bidx[s], (float)bidx[d]);
        } else if (lane8 == 1) {
            const float dd = p + bias_d;                 // z0 - z1
            const float ad = fabsf(dd);
            const float t = -log1pf(expf(-ad));
            const float2 pr = (dd >= 0.f) ? make_float2(t, t - ad) : make_float2(t - ad, t);
            *reinterpret_cast<float2*>(&out_probs[(size_t)e * 2]) = pr;
        }

        if (!more) break;
        e = e2; s = s2; d = d2; ua = ua2; va = va2;
    }
}

extern "C" void kernel_launch(void* const* d_in, const int* in_sizes, int n_in,
                              void* d_out, int out_size, void* d_ws, size_t ws_size,
                              hipStream_t stream) {
    const float* feat   = (const float*)d_in[0];
    const float* bboxes = (const float*)d_in[1];
    const int*   bidx   = (const int*)d_in[2];
    const int*   eidx   = (const int*)d_in[3];
    const float* W1     = (const float*)d_in[4];
    const float* b1     = (const float*)d_in[5];
    const float* W2     = (const float*)d_in[6];
    const float* b2     = (const float*)d_in[7];
    const float* lin1W  = (const float*)d_in[8];
    const float* lin1b  = (const float*)d_in[9];
    const float* linfW  = (const float*)d_in[10];
    const float* linfb  = (const float*)d_in[11];

    const int N = in_sizes[0] / 8;
    const int E = in_sizes[3] / 2;
    const int* row = eidx;        // sources
    const int* col = eidx + E;    // targets

    size_t Np = ((size_t)N + 255) & ~255ull;
    size_t Ep = ((size_t)E + 255) & ~255ull;
    int*    cnt    = (int*)d_ws;                 // Np
    int*    cursor = cnt + Np;                   // Np (zeroed with cnt)
    int*    ptr    = cursor + Np;                // Np+256
    int*    bsum   = ptr + Np + 256;             // 256
    int2*   eadj   = (int2*)(bsum + 256);        // Ep int2 (src, norm-bits)
    ushort* x1     = (ushort*)(eadj + Ep);       // N*128 bf16 (re-used as xbf)
    uchar*  h2     = (uchar*)(x1 + (size_t)N * 128);   // N*128 fp8
    uchar*  uvbuf  = h2 + (size_t)N * 128;       // N*256 fp8
    ushort* Wuv    = (ushort*)(uvbuf + (size_t)N * 256); // 256*128 bf16
    ushort* W2t    = Wuv + 256 * 128;            // 128*128 bf16
    ushort* xbf    = x1;                         // alias: x1 dead after k_gemm2

    float* out       = (float*)d_out;
    float* out_probs = out;                   // E*2
    float* out_bbox  = out + (size_t)E * 2;   // E*8
    float* out_bidx  = out + (size_t)E * 10;  // E*2

    const int B = 256;
    const int nchunk = (N + 2047) / 2048;

    // CSR build + weight prep
    hipMemsetAsync(cnt, 0, 2 * Np * sizeof(int), stream);   // cnt + cursor
    k_hist<<<(E + B - 1) / B, B, 0, stream>>>(col, cnt, E);
    k_bsum<<<nchunk, 1024, 0, stream>>>(cnt, bsum, N);
    k_scanw<<<nchunk, 1024, 0, stream>>>(cnt, bsum, ptr, N, E);
    k_fill<<<(E + B - 1) / B, B, 0, stream>>>(row, col, cnt, ptr, cursor, eadj, E);
    k_prepW<<<(256 * 128 + 128 * 128 + B - 1) / B, B, 0, stream>>>(lin1W, W2, Wuv, W2t);

    // layer 1 fused (aggregate + GEMM)
    k_l1<<<(N + 31) / 32, B, 0, stream>>>(feat, cnt, ptr, eadj, W1, b1, x1, N);

    // layer 2 (MFMA GEMM -> fp8 h2, then 8-lane fp8 gather; xbf aliases x1)
    k_gemm2<<<(N + 63) / 64, B, 0, stream>>>(x1, W2t, h2, N);
    k_gather2<<<(N + 31) / 32, B, 0, stream>>>(h2, cnt, ptr, eadj, b2, xbf, N);

    // per-node edge-MLP projections: uv = fp8(xbf @ [W_top|W_bot]), bias folded into u
    k_gemm_uv<<<(N + 127) / 128, 512, 0, stream>>>(xbf, Wuv, lin1b, uvbuf, N);

    // per-edge epilogue + outputs (8 lanes/edge, pipelined, flat order = coalesced writes)
    k_edge_lite<<<2048, B, 0, stream>>>(uvbuf, linfW, linfb,
                                        bboxes, bidx, row, col,
                                        out_probs, out_bbox, out_bidx, E);
}